// Round 1
// baseline (129.314 us; speedup 1.0000x reference)
//
#include <hip/hip_runtime.h>

// CostConcatenation: out[b,d,h,w, 0:16] = left[b,h,w,:]        (if valid else 0)
//                    out[b,d,h,w,16:32] = right[b,h,w-disp,:]  (if valid else 0)
// disp = d + MIN_DISP = d - 112 ; idx = w - disp = w - d + 112 ; valid = 0<=idx<W
// Output shape (B, D, H, W, 2C) fp32 = 604 MB -> write-BW bound.

constexpr int B_ = 2;
constexpr int H_ = 96;
constexpr int W_ = 192;
constexpr int D_ = 128;
// C = 16 floats per half -> 4 float4 per half, 8 float4 per (b,d,h,w) cell.

__global__ __launch_bounds__(256) void cost_concat_kernel(
    const float4* __restrict__ left,
    const float4* __restrict__ right,
    float4* __restrict__ out)
{
    const int h = blockIdx.x;   // grid = (H, D, B) -> no integer division at all
    const int d = blockIdx.y;
    const int b = blockIdx.z;

    // input row base in float4 units: row (b,h) has W*4 float4s
    const int rowBase = (b * H_ + h) * (W_ * 4);
    // output row base in float4 units: row (b,d,h) has W*8 float4s
    const long long outBase = (((long long)(b * D_ + d)) * H_ + h) * (long long)(W_ * 8);

    const int shift = 112 - d;  // idx = w + shift

    // W*8 = 1536 float4 per row, 256 threads -> 6 iterations, fully coalesced
    #pragma unroll
    for (int j = threadIdx.x; j < W_ * 8; j += 256) {
        const int w  = j >> 3;   // cell within row
        const int c4 = j & 7;    // which float4 within the 32-float cell
        const int idx = w + shift;

        float4 v = make_float4(0.f, 0.f, 0.f, 0.f);
        if ((unsigned)idx < (unsigned)W_) {
            // pointer select (cndmask), single load predicated on valid
            const float4* src = (c4 < 4)
                ? (left  + rowBase + w   * 4 + c4)
                : (right + rowBase + idx * 4 + (c4 - 4));
            v = *src;
        }
        out[outBase + j] = v;
    }
}

extern "C" void kernel_launch(void* const* d_in, const int* in_sizes, int n_in,
                              void* d_out, int out_size, void* d_ws, size_t ws_size,
                              hipStream_t stream)
{
    const float4* left  = (const float4*)d_in[0];
    const float4* right = (const float4*)d_in[1];
    float4* out = (float4*)d_out;

    dim3 grid(H_, D_, B_);   // 96 * 128 * 2 = 24576 blocks, 24 KB contiguous writes each
    cost_concat_kernel<<<grid, 256, 0, stream>>>(left, right, out);
}

// Round 3
// 118.016 us; speedup vs baseline: 1.0957x; 1.0957x over previous
//
#include <hip/hip_runtime.h>

// CostConcatenation: out[b,d,h,w, 0:16] = left[b,h,w,:]        (if valid else 0)
//                    out[b,d,h,w,16:32] = right[b,h,w-disp,:]  (if valid else 0)
// disp = d + MIN_DISP = d - 112 ; idx = w - disp = w - d + 112 ; valid = 0<=idx<W
// Output (B, D, H, W, 2C) fp32 = 604 MB -> pure write-BW bound.
// R1/R3: non-temporal stores for the 604 MB output stream (never re-read;
// keep L2 for the 4.7 MB of inputs that 128 d-blocks per (b,h) re-read).
// R3 fix: __builtin_nontemporal_store needs a NATIVE vector type, not
// HIP_vector_type -> use ext_vector_type(4) float.

constexpr int B_ = 2;
constexpr int H_ = 96;
constexpr int W_ = 192;
constexpr int D_ = 128;

typedef float v4f __attribute__((ext_vector_type(4)));

__global__ __launch_bounds__(256) void cost_concat_kernel(
    const v4f* __restrict__ left,
    const v4f* __restrict__ right,
    v4f* __restrict__ out)
{
    const int h = blockIdx.x;   // grid = (H, D, B): no integer division anywhere
    const int d = blockIdx.y;
    const int b = blockIdx.z;

    const int rowBase = (b * H_ + h) * (W_ * 4);            // float4 units
    const long long outBase =
        (((long long)(b * D_ + d)) * H_ + h) * (long long)(W_ * 8);

    const int shift = 112 - d;  // idx = w + shift

    const v4f* __restrict__ lrow = left  + rowBase;
    const v4f* __restrict__ rrow = right + rowBase;
    v4f* __restrict__ orow = out + outBase;

    // W*8 = 1536 float4 per row, 256 threads -> 6 fully-unrolled iterations
    #pragma unroll
    for (int j = threadIdx.x; j < W_ * 8; j += 256) {
        const int w  = j >> 3;   // cell within row
        const int c4 = j & 7;    // which float4 within the 32-float cell
        const int idx = w + shift;

        v4f v = (v4f)(0.f);
        if ((unsigned)idx < (unsigned)W_) {
            const v4f* src = (c4 < 4)
                ? (lrow + w   * 4 + c4)
                : (rrow + idx * 4 + (c4 - 4));
            v = *src;
        }
        __builtin_nontemporal_store(v, orow + j);
    }
}

extern "C" void kernel_launch(void* const* d_in, const int* in_sizes, int n_in,
                              void* d_out, int out_size, void* d_ws, size_t ws_size,
                              hipStream_t stream)
{
    const v4f* left  = (const v4f*)d_in[0];
    const v4f* right = (const v4f*)d_in[1];
    v4f* out = (v4f*)d_out;

    dim3 grid(H_, D_, B_);   // 96 * 128 * 2 = 24576 blocks, 24 KB contiguous writes each
    cost_concat_kernel<<<grid, 256, 0, stream>>>(left, right, out);
}